// Round 8
// baseline (311.721 us; speedup 1.0000x reference)
//
#include <hip/hip_runtime.h>

typedef __attribute__((ext_vector_type(8))) short short8v;
typedef __attribute__((ext_vector_type(4))) short short4v;
typedef __attribute__((ext_vector_type(4))) float float4v;
typedef __attribute__((ext_vector_type(4))) unsigned short ushort4v;
typedef __attribute__((ext_vector_type(8))) unsigned short ushort8v;

#define GLOBAL_AS __attribute__((address_space(1)))
#define LDS_AS __attribute__((address_space(3)))

__device__ __forceinline__ void async_cp16(const void* g, void* l) {
  __builtin_amdgcn_global_load_lds((const GLOBAL_AS void*)g, (LDS_AS void*)l, 16, 0, 0);
}

__device__ __forceinline__ unsigned short f2bf(float f) {
  unsigned u = __float_as_uint(f);
  u += 0x7fffu + ((u >> 16) & 1u);   // RNE to bf16
  return (unsigned short)(u >> 16);
}

// amdgcn target-builtins are invisible in the host pass — gate all probes.
#if defined(__HIP_DEVICE_COMPILE__)
#if __has_builtin(__builtin_amdgcn_exp2f)
#define EXP2F(x) __builtin_amdgcn_exp2f(x)
#else
#define EXP2F(x) exp2f(x)
#endif
#else
#define EXP2F(x) exp2f(x)
#endif

#if defined(__HIP_DEVICE_COMPILE__) && __has_builtin(__builtin_amdgcn_cvt_pk_bf16_f32)
typedef __attribute__((ext_vector_type(2))) __bf16 bf16x2v;
__device__ __forceinline__ unsigned pk_bf16(float a, float b) {
  bf16x2v r = __builtin_amdgcn_cvt_pk_bf16_f32(a, b);
  return __builtin_bit_cast(unsigned, r);
}
#else
__device__ __forceinline__ unsigned pk_bf16(float a, float b) {
  return (unsigned)f2bf(a) | ((unsigned)f2bf(b) << 16);
}
#endif

#define MFMA_QK(a, b, c) __builtin_amdgcn_mfma_f32_16x16x32_bf16(a, b, c, 0, 0, 0)

// Raw workgroup barrier with compiler memory fence (no implicit vmcnt(0) drain).
__device__ __forceinline__ void wg_barrier() {
  asm volatile("" ::: "memory");
  __builtin_amdgcn_s_barrier();
  asm volatile("" ::: "memory");
}

// ---------------------------------------------------------------- converters

__global__ __launch_bounds__(256) void cvt_f32_bf16(const float* __restrict__ src,
                                                    unsigned short* __restrict__ dst) {
  int i = blockIdx.x * 256 + threadIdx.x;
  float4 v = ((const float4*)src)[i];
  ushort4v o;
  o.x = f2bf(v.x); o.y = f2bf(v.y); o.z = f2bf(v.z); o.w = f2bf(v.w);
  ((ushort4v*)dst)[i] = o;
}

// src: K x N fp32  ->  dst: N x K bf16 (transposed)
__global__ __launch_bounds__(256) void transpose_w(const float* __restrict__ src,
                                                   unsigned short* __restrict__ dst,
                                                   int K, int N) {
  __shared__ float tile[64][65];
  int k0 = blockIdx.x * 64, n0 = blockIdx.y * 64;
  int t = threadIdx.x;
  int tc = t & 15, tr = t >> 4;
#pragma unroll
  for (int p = 0; p < 4; p++) {
    int r = tr + p * 16;
    float4 v = *(const float4*)(src + (size_t)(k0 + r) * N + n0 + tc * 4);
    tile[r][tc * 4 + 0] = v.x; tile[r][tc * 4 + 1] = v.y;
    tile[r][tc * 4 + 2] = v.z; tile[r][tc * 4 + 3] = v.w;
  }
  __syncthreads();
#pragma unroll
  for (int p = 0; p < 4; p++) {
    int rn = tr + p * 16;
    ushort4v o;
    o.x = f2bf(tile[tc * 4 + 0][rn]);
    o.y = f2bf(tile[tc * 4 + 1][rn]);
    o.z = f2bf(tile[tc * 4 + 2][rn]);
    o.w = f2bf(tile[tc * 4 + 3][rn]);
    *(ushort4v*)(dst + (size_t)(n0 + rn) * K + k0 + tc * 4) = o;
  }
}

// ---------------------------------------------------------------- GEMM staging
// Swizzle (HW-verified 0 bank conflicts in R2): physical 16B slot s of row
// holds logical chunk s ^ ((row>>1)&3). global_load_lds dest stays linear;
// the GLOBAL source is pre-swizzled; ds_read applies the same XOR.
// 128 rows x 32 cols bf16, 256 threads, 2 cp16/thread.
__device__ __forceinline__ void stage128x32(const unsigned short* __restrict__ src,
                                            unsigned short* dst, int r0, int k0, int tid) {
#pragma unroll
  for (int p = 0; p < 2; p++) {
    int idx = p * 256 + tid;
    int row = idx >> 2, s = idx & 3;
    int ch = s ^ ((row >> 1) & 3);
    async_cp16(src + (size_t)(r0 + row) * 1024 + k0 + ch * 8, dst + idx * 8);
  }
}

// ---------------------------------------------------------------- QKV GEMM
// R15: counted-vmcnt 3-buffer pipeline at the R1 geometry (128x128, 256
// threads, BK=32, 48 KB LDS -> 3 blocks/CU). Iteration t reads buf t%3,
// stages tile t+2 into buf (t+2)%3; boundary wait vmcnt(4) keeps t+2's
// loads in flight across the barrier (T4).
// Q is pre-scaled by 0.125*log2(e); V tokens pre-permuted per 32-group:
// position p holds token ((p>>2)&1)*16 + (p>>3)*4 + (p&3); V-blocks
// transpose through LDS and write VT as full 16B/lane stores (R12).

#define TT_STRIDE 136  // ushorts per tile_T row (272 B): breaks bank alignment

__global__ __launch_bounds__(256) void gemm_qkv(const unsigned short* __restrict__ A,
                                                const unsigned short* __restrict__ BT,
                                                const float* __restrict__ bias,
                                                unsigned short* __restrict__ Qo,
                                                unsigned short* __restrict__ Ko,
                                                unsigned short* __restrict__ VTo) {
  // 48 KB: 3 A-bufs + 3 B-bufs of 128x32 bf16. The V-transpose tile
  // (17408 ushorts) aliases the whole region after the k-loop.
  __shared__ unsigned short smem[24576];
  int tid = threadIdx.x;
  int lane = tid & 63, w = tid >> 6, g = lane >> 4, c = lane & 15;
  int m0 = blockIdx.x * 128, n0 = blockIdx.y * 128;
  int wm = (w & 1) * 64, wn = (w >> 1) * 64;
  float4v acc[4][4] = {};

  // prologue: stage tiles 0 and 1 (8 DMAs/thread)
  stage128x32(A, smem + 0 * 4096, m0, 0, tid);
  stage128x32(BT, smem + 12288 + 0 * 4096, n0, 0, tid);
  stage128x32(A, smem + 1 * 4096, m0, 32, tid);
  stage128x32(BT, smem + 12288 + 1 * 4096, n0, 32, tid);
  asm volatile("s_waitcnt vmcnt(4)" ::: "memory");  // tile 0 landed; tile 1 in flight
  wg_barrier();

  int cb = 0;
  for (int t = 0; t < 32; ++t) {
    int nb = cb + 2; if (nb >= 3) nb -= 3;  // buffer of tile t+2
    const unsigned short* Ap = smem + cb * 4096;
    const unsigned short* Bp = smem + 12288 + cb * 4096;

    short8v af[4], bf[4];
#pragma unroll
    for (int i = 0; i < 4; i++) {
      int r = wm + i * 16 + c;
      af[i] = *(const short8v*)(Ap + r * 32 + (g ^ ((r >> 1) & 3)) * 8);
    }
#pragma unroll
    for (int j = 0; j < 4; j++) {
      int r = wn + j * 16 + c;
      bf[j] = *(const short8v*)(Bp + r * 32 + (g ^ ((r >> 1) & 3)) * 8);
    }

    if (t + 2 < 32) {
      stage128x32(A, smem + nb * 4096, m0, (t + 2) * 32, tid);
      stage128x32(BT, smem + 12288 + nb * 4096, n0, (t + 2) * 32, tid);
    }

    __builtin_amdgcn_s_setprio(1);
#pragma unroll
    for (int i = 0; i < 4; i++)
#pragma unroll
      for (int j = 0; j < 4; j++)
        acc[i][j] = MFMA_QK(af[i], bf[j], acc[i][j]);
    __builtin_amdgcn_s_setprio(0);

    if (t < 30) { asm volatile("s_waitcnt vmcnt(4)" ::: "memory"); }
    else        { asm volatile("s_waitcnt vmcnt(0)" ::: "memory"); }
    wg_barrier();
    cb = cb + 1 == 3 ? 0 : cb + 1;
  }

  int which = n0 >> 10;  // 0=Q 1=K 2=V, uniform per block
  if (which != 2) {
    // Q/K: direct writes ([b,h,n,d], 32B chunks; adjacent j-stores merge in L2)
#pragma unroll
    for (int j = 0; j < 4; j++) {
      int ng = n0 + wn + j * 16 + c;
      float bv = bias[ng];
      int h = (ng & 1023) >> 6, d = ng & 63;
#pragma unroll
      for (int i = 0; i < 4; i++) {
#pragma unroll
        for (int r = 0; r < 4; r++) {
          int mg = m0 + wm + i * 16 + g * 4 + r;
          int b = mg >> 11, n = mg & 2047;
          float v = acc[i][j][r] + bv;
          if (which == 0)
            Qo[((size_t)(b * 16 + h) * 2048 + n) * 64 + d] = f2bf(v * 0.18033688011112042f);
          else
            Ko[((size_t)(b * 16 + h) * 2048 + n) * 64 + d] = f2bf(v);
        }
      }
    }
  } else {
    // V: transpose through LDS -> full-line n-major VT writes.
    __syncthreads();  // k-loop fully done; safe to reuse smem as tile_T
#pragma unroll
    for (int j = 0; j < 4; j++) {
      int nl = wn + j * 16 + c;          // n_local = hl*64 + d
      float bv = bias[n0 + nl];
#pragma unroll
      for (int i = 0; i < 4; i++) {
        int ml = wm + i * 16 + g * 4;    // token_local (4 consecutive via r)
        unsigned p0 = pk_bf16(acc[i][j][0] + bv, acc[i][j][1] + bv);
        unsigned p1 = pk_bf16(acc[i][j][2] + bv, acc[i][j][3] + bv);
        *(unsigned*)(smem + nl * TT_STRIDE + ml) = p0;
        *(unsigned*)(smem + nl * TT_STRIDE + ml + 2) = p1;
      }
    }
    __syncthreads();
    // write phase: 16B/lane = permuted-octet gather (tokens P*4+0..3 and +16)
    int rr = lane >> 4, tc = lane & 15;
    int P = tc & 3, g32 = tc >> 2;
    int b = m0 >> 11, mloc = m0 & 2047;
    int h0 = (n0 & 1023) >> 6;
#pragma unroll
    for (int s = 0; s < 8; s++) {
      int row = w * 32 + s * 4 + rr;     // n_local
      int h = h0 + (row >> 6), d = row & 63;
      const unsigned short* bp = smem + row * TT_STRIDE + g32 * 32 + P * 4;
      union { unsigned long long q[2]; ushort8v v; } u;
      u.q[0] = *(const unsigned long long*)(bp);
      u.q[1] = *(const unsigned long long*)(bp + 16);
      size_t gaddr = ((size_t)(b * 16 + h) * 64 + d) * 2048 + mloc + g32 * 32 + P * 8;
      *(ushort8v*)(VTo + gaddr) = u.v;
    }
  }
}

// ---------------------------------------------------------------- attention
// R16: 32 q-rows/wave -> 4096 waves -> grid 1024 (4 blocks/CU, 16 waves/CU,
// 4 waves/SIMD; was 2) for cross-wave MFMA/exp(trans) pipe mixing — attn has
// been stall-bound (~49% idle) at 2 waves/SIMD across 4 structural variants.
// K stays in LDS (critical path; dbuf 16 KB/block, verified swizzle).
// V comes DIRECT FROM GLOBAL into regs (the R13 path, HW-verified): issued
// at 32-key-group start, consumed ~700cyc later after QK+exp -> L2 latency
// hidden; L1 filters the 4-waves-per-block duplication. Halves LDS reads and
// removes V-staging DMAs, so LDS traffic stays flat despite 2x waves.
// __launch_bounds__(256,4) pins VGPR<=128 for the 4/SIMD bucket.

#define NTOK 2048
#define BK 64

__device__ __forceinline__ short8v exppack(float4v a, float4v b2) {
  a.x = EXP2F(a.x); a.y = EXP2F(a.y); a.z = EXP2F(a.z); a.w = EXP2F(a.w);
  b2.x = EXP2F(b2.x); b2.y = EXP2F(b2.y); b2.z = EXP2F(b2.z); b2.w = EXP2F(b2.w);
  union { unsigned u[4]; short8v s; } cv;
  cv.u[0] = pk_bf16(a.x, a.y);
  cv.u[1] = pk_bf16(a.z, a.w);
  cv.u[2] = pk_bf16(b2.x, b2.y);
  cv.u[3] = pk_bf16(b2.z, b2.w);
  return cv.s;
}

__global__ __launch_bounds__(256, 4) void attn_kernel(const unsigned short* __restrict__ Qg,
                                                      const unsigned short* __restrict__ Kg,
                                                      const unsigned short* __restrict__ VTg,
                                                      unsigned short* __restrict__ Og) {
  __shared__ unsigned short Ks[2][BK * 64];   // K only: 16 KB, row-XOR swizzled

  int tid = threadIdx.x;
  int lane = tid & 63, w = tid >> 6, g = lane >> 4, c = lane & 15;
  // XCD-locality swizzle: 1024 blocks = 8 XCDs x (8 bh) x (16 q-chunks of 128)
  int id = blockIdx.x;
  int xcd = id & 7, within = id >> 3;
  int bh = xcd * 8 + (within >> 4);
  int q0 = (within & 15) * 128;

  const unsigned short* Qb = Qg + (size_t)bh * NTOK * 64;
  const unsigned short* Kb = Kg + (size_t)bh * NTOK * 64;
  const unsigned short* VTb = VTg + (size_t)bh * 64 * NTOK;

  // Q fragments straight from global (one-time); 32 rows per wave
  short8v qf[2][2];
#pragma unroll
  for (int nt = 0; nt < 2; nt++)
#pragma unroll
    for (int kk = 0; kk < 2; kk++)
      qf[nt][kk] = *(const short8v*)(Qb + (size_t)(q0 + w * 32 + nt * 16 + c) * 64 +
                                     kk * 32 + g * 8);

  short8v ones8;
#pragma unroll
  for (int i = 0; i < 8; i++) ones8[i] = (short)0x3F80;

  float4v lacc[2] = {};
  float4v o[2][4] = {};

  // per-lane V base: 16B unit nt_o covers this lane's 8 keys of a 32-chunk
  // (R13 path, HW-verified; V tokens pre-permuted per 32-group by gemm_qkv)
  const unsigned short* vbase = VTb + (size_t)c * 2048 + g * 8;

  // prologue: stage K tile 0 into buf 0
#pragma unroll
  for (int p = 0; p < 2; p++) {
    int idx = p * 256 + tid;
    int row = idx >> 3, ch = idx & 7;
    async_cp16(Kb + (size_t)row * 64 + ((ch ^ (row & 7)) * 8), &Ks[0][idx * 8]);
  }

  for (int it = 0; it < NTOK / BK; it++) {
    int pb = it & 1;
    __syncthreads();  // drains own DMAs for tile it (issued a full phase ago)

    if (it + 1 < NTOK / BK) {
      int kt = (it + 1) * BK;
#pragma unroll
      for (int p = 0; p < 2; p++) {
        int idx = p * 256 + tid;
        int row = idx >> 3, ch = idx & 7;
        async_cp16(Kb + (size_t)(kt + row) * 64 + ((ch ^ (row & 7)) * 8),
                   &Ks[1 - pb][idx * 8]);
      }
    }

    const unsigned short* Kp = &Ks[pb][0];

    // two 32-key groups per tile
#pragma unroll
    for (int t = 0; t < 2; t++) {
      int ch32 = it * 2 + t;
      // V loads first (global/L2) — consumed after QK+exp, latency hidden
      short8v vb[4];
#pragma unroll
      for (int nt_o = 0; nt_o < 4; nt_o++)
        vb[nt_o] = *(const short8v*)(vbase + (size_t)nt_o * 32768 + ch32 * 32);

      float4v st[2][2] = {};
      __builtin_amdgcn_s_setprio(1);
#pragma unroll
      for (int mth = 0; mth < 2; mth++) {
        int row = (t * 2 + mth) * 16 + c;
        short8v kf[2];
#pragma unroll
        for (int kk = 0; kk < 2; kk++) {
          int ch = (kk * 4 + g) ^ (row & 7);
          kf[kk] = *(const short8v*)(Kp + row * 64 + ch * 8);
        }
#pragma unroll
        for (int nt = 0; nt < 2; nt++)
#pragma unroll
          for (int kk = 0; kk < 2; kk++)
            st[mth][nt] = MFMA_QK(kf[kk], qf[nt][kk], st[mth][nt]);
      }
      __builtin_amdgcn_s_setprio(0);

      short8v pa8[2];
#pragma unroll
      for (int nt = 0; nt < 2; nt++) pa8[nt] = exppack(st[0][nt], st[1][nt]);

      __builtin_amdgcn_s_setprio(1);
#pragma unroll
      for (int nt_o = 0; nt_o < 4; nt_o++)
#pragma unroll
        for (int mt = 0; mt < 2; mt++)
          o[mt][nt_o] = MFMA_QK(pa8[mt], vb[nt_o], o[mt][nt_o]);
#pragma unroll
      for (int mt = 0; mt < 2; mt++)
        lacc[mt] = MFMA_QK(pa8[mt], ones8, lacc[mt]);
      __builtin_amdgcn_s_setprio(0);
    }
  }

  // epilogue: lacc[mt][r] = L[q] in exactly o's row layout; no cross-lane
  int b = bh >> 4, h = bh & 15;
#pragma unroll
  for (int mt = 0; mt < 2; mt++) {
    float4v li;
#pragma unroll
    for (int r = 0; r < 4; r++) li[r] = 1.0f / lacc[mt][r];
#pragma unroll
    for (int nt_o = 0; nt_o < 4; nt_o++) {
      float4v v = o[mt][nt_o] * li;
      int col = h * 64 + nt_o * 16 + c;
      int rowbase = b * NTOK + q0 + w * 32 + mt * 16 + g * 4;
#pragma unroll
      for (int r = 0; r < 4; r++)
        Og[(size_t)(rowbase + r) * 1024 + col] = f2bf(v[r]);
    }
  }
}

// ---------------------------------------------------------------- proj GEMM
// R15: same counted-vmcnt 3-buffer pipeline at 128x128 / 256 threads.
__global__ __launch_bounds__(256) void gemm_proj(const unsigned short* __restrict__ A,
                                                 const unsigned short* __restrict__ BT,
                                                 const float* __restrict__ bias,
                                                 float* __restrict__ out) {
  __shared__ unsigned short smem[24576];  // 3 A-bufs + 3 B-bufs
  int tid = threadIdx.x;
  int lane = tid & 63, w = tid >> 6, g = lane >> 4, c = lane & 15;
  int m0 = blockIdx.x * 128, n0 = blockIdx.y * 128;
  int wm = (w & 1) * 64, wn = (w >> 1) * 64;
  float4v acc[4][4] = {};

  stage128x32(A, smem + 0 * 4096, m0, 0, tid);
  stage128x32(BT, smem + 12288 + 0 * 4096, n0, 0, tid);
  stage128x32(A, smem + 1 * 4096, m0, 32, tid);
  stage128x32(BT, smem + 12288 + 1 * 4096, n0, 32, tid);
  asm volatile("s_waitcnt vmcnt(4)" ::: "memory");
  wg_barrier();

  int cb = 0;
  for (int t = 0; t < 32; ++t) {
    int nb = cb + 2; if (nb >= 3) nb -= 3;
    const unsigned short* Ap = smem + cb * 4096;
    const unsigned short* Bp = smem + 12288 + cb * 4096;

    short8v af[4], bf[4];
#pragma unroll
    for (int i = 0; i < 4; i++) {
      int r = wm + i * 16 + c;
      af[i] = *(const short8v*)(Ap + r * 32 + (g ^ ((r >> 1) & 3)) * 8);
    }
#pragma unroll
    for (int j = 0; j < 4; j++) {
      int r = wn + j * 16 + c;
      bf[j] = *(const short8v*)(Bp + r * 32 + (g ^ ((r >> 1) & 3)) * 8);
    }

    if (t + 2 < 32) {
      stage128x32(A, smem + nb * 4096, m0, (t + 2) * 32, tid);
      stage128x32(BT, smem + 12288 + nb * 4096, n0, (t + 2) * 32, tid);
    }

    __builtin_amdgcn_s_setprio(1);
#pragma unroll
    for (int i = 0; i < 4; i++)
#pragma unroll
      for (int j = 0; j < 4; j++)
        acc[i][j] = MFMA_QK(af[i], bf[j], acc[i][j]);
    __builtin_amdgcn_s_setprio(0);

    if (t < 30) { asm volatile("s_waitcnt vmcnt(4)" ::: "memory"); }
    else        { asm volatile("s_waitcnt vmcnt(0)" ::: "memory"); }
    wg_barrier();
    cb = cb + 1 == 3 ? 0 : cb + 1;
  }

#pragma unroll
  for (int j = 0; j < 4; j++) {
    int ng = n0 + wn + j * 16 + c;
    float bv = bias[ng];
#pragma unroll
    for (int i = 0; i < 4; i++) {
#pragma unroll
      for (int r = 0; r < 4; r++) {
        int mg = m0 + wm + i * 16 + g * 4 + r;
        out[(size_t)mg * 1024 + ng] = acc[i][j][r] + bv;
      }
    }
  }
}

// ---------------------------------------------------------------- launch

extern "C" void kernel_launch(void* const* d_in, const int* in_sizes, int n_in,
                              void* d_out, int out_size, void* d_ws, size_t ws_size,
                              hipStream_t stream) {
  (void)in_sizes; (void)n_in; (void)out_size; (void)ws_size;
  const float* x = (const float*)d_in[0];
  const float* w_qkv = (const float*)d_in[1];
  const float* b_qkv = (const float*)d_in[2];
  const float* w_proj = (const float*)d_in[3];
  const float* b_proj = (const float*)d_in[4];
  float* out = (float*)d_out;

  unsigned short* x_bf = (unsigned short*)d_ws;          // 8192*1024
  unsigned short* wqkvT = x_bf + (size_t)8192 * 1024;    // 3072*1024
  unsigned short* wprojT = wqkvT + (size_t)3072 * 1024;  // 1024*1024
  unsigned short* qws = wprojT + (size_t)1024 * 1024;    // 64*2048*64
  unsigned short* kws = qws + (size_t)8388608;
  unsigned short* vtws = kws + (size_t)8388608;
  unsigned short* aws = vtws + (size_t)8388608;          // attn out 8192*1024

  cvt_f32_bf16<<<8192, 256, 0, stream>>>(x, x_bf);
  transpose_w<<<dim3(16, 48), 256, 0, stream>>>(w_qkv, wqkvT, 1024, 3072);
  transpose_w<<<dim3(16, 16), 256, 0, stream>>>(w_proj, wprojT, 1024, 1024);
  gemm_qkv<<<dim3(64, 24), 256, 0, stream>>>(x_bf, wqkvT, b_qkv, qws, kws, vtws);
  attn_kernel<<<1024, 256, 0, stream>>>(qws, kws, vtws, aws);
  gemm_proj<<<dim3(64, 8), 256, 0, stream>>>(aws, wprojT, b_proj, out);
}

// Round 9
// 268.387 us; speedup vs baseline: 1.1615x; 1.1615x over previous
//
#include <hip/hip_runtime.h>

typedef __attribute__((ext_vector_type(8))) short short8v;
typedef __attribute__((ext_vector_type(4))) short short4v;
typedef __attribute__((ext_vector_type(4))) float float4v;
typedef __attribute__((ext_vector_type(4))) unsigned short ushort4v;
typedef __attribute__((ext_vector_type(8))) unsigned short ushort8v;

#define GLOBAL_AS __attribute__((address_space(1)))
#define LDS_AS __attribute__((address_space(3)))

__device__ __forceinline__ void async_cp16(const void* g, void* l) {
  __builtin_amdgcn_global_load_lds((const GLOBAL_AS void*)g, (LDS_AS void*)l, 16, 0, 0);
}

__device__ __forceinline__ unsigned short f2bf(float f) {
  unsigned u = __float_as_uint(f);
  u += 0x7fffu + ((u >> 16) & 1u);   // RNE to bf16
  return (unsigned short)(u >> 16);
}

// amdgcn target-builtins are invisible in the host pass — gate all probes.
#if defined(__HIP_DEVICE_COMPILE__)
#if __has_builtin(__builtin_amdgcn_exp2f)
#define EXP2F(x) __builtin_amdgcn_exp2f(x)
#else
#define EXP2F(x) exp2f(x)
#endif
#else
#define EXP2F(x) exp2f(x)
#endif

#if defined(__HIP_DEVICE_COMPILE__) && __has_builtin(__builtin_amdgcn_cvt_pk_bf16_f32)
typedef __attribute__((ext_vector_type(2))) __bf16 bf16x2v;
__device__ __forceinline__ unsigned pk_bf16(float a, float b) {
  bf16x2v r = __builtin_amdgcn_cvt_pk_bf16_f32(a, b);
  return __builtin_bit_cast(unsigned, r);
}
#else
__device__ __forceinline__ unsigned pk_bf16(float a, float b) {
  return (unsigned)f2bf(a) | ((unsigned)f2bf(b) << 16);
}
#endif

#define MFMA_QK(a, b, c) __builtin_amdgcn_mfma_f32_16x16x32_bf16(a, b, c, 0, 0, 0)

// Raw workgroup barrier with compiler memory fence (no implicit vmcnt(0) drain).
__device__ __forceinline__ void wg_barrier() {
  asm volatile("" ::: "memory");
  __builtin_amdgcn_s_barrier();
  asm volatile("" ::: "memory");
}

// ---------------------------------------------------------------- converters

__global__ __launch_bounds__(256) void cvt_f32_bf16(const float* __restrict__ src,
                                                    unsigned short* __restrict__ dst) {
  int i = blockIdx.x * 256 + threadIdx.x;
  float4 v = ((const float4*)src)[i];
  ushort4v o;
  o.x = f2bf(v.x); o.y = f2bf(v.y); o.z = f2bf(v.z); o.w = f2bf(v.w);
  ((ushort4v*)dst)[i] = o;
}

// src: K x N fp32  ->  dst: N x K bf16 (transposed)
__global__ __launch_bounds__(256) void transpose_w(const float* __restrict__ src,
                                                   unsigned short* __restrict__ dst,
                                                   int K, int N) {
  __shared__ float tile[64][65];
  int k0 = blockIdx.x * 64, n0 = blockIdx.y * 64;
  int t = threadIdx.x;
  int tc = t & 15, tr = t >> 4;
#pragma unroll
  for (int p = 0; p < 4; p++) {
    int r = tr + p * 16;
    float4 v = *(const float4*)(src + (size_t)(k0 + r) * N + n0 + tc * 4);
    tile[r][tc * 4 + 0] = v.x; tile[r][tc * 4 + 1] = v.y;
    tile[r][tc * 4 + 2] = v.z; tile[r][tc * 4 + 3] = v.w;
  }
  __syncthreads();
#pragma unroll
  for (int p = 0; p < 4; p++) {
    int rn = tr + p * 16;
    ushort4v o;
    o.x = f2bf(tile[tc * 4 + 0][rn]);
    o.y = f2bf(tile[tc * 4 + 1][rn]);
    o.z = f2bf(tile[tc * 4 + 2][rn]);
    o.w = f2bf(tile[tc * 4 + 3][rn]);
    *(ushort4v*)(dst + (size_t)(n0 + rn) * K + k0 + tc * 4) = o;
  }
}

// ---------------------------------------------------------------- GEMM staging
// Swizzle (HW-verified 0 bank conflicts in R2): physical 16B slot s of row
// holds logical chunk s ^ ((row>>1)&3). global_load_lds dest stays linear;
// the GLOBAL source is pre-swizzled; ds_read applies the same XOR.
// 128 rows x 32 cols bf16, 256 threads, 2 cp16/thread.
__device__ __forceinline__ void stage128x32(const unsigned short* __restrict__ src,
                                            unsigned short* dst, int r0, int k0, int tid) {
#pragma unroll
  for (int p = 0; p < 2; p++) {
    int idx = p * 256 + tid;
    int row = idx >> 2, s = idx & 3;
    int ch = s ^ ((row >> 1) & 3);
    async_cp16(src + (size_t)(r0 + row) * 1024 + k0 + ch * 8, dst + idx * 8);
  }
}

// ---------------------------------------------------------------- QKV GEMM
// R15: counted-vmcnt 3-buffer pipeline at the R1 geometry (128x128, 256
// threads, BK=32, 48 KB LDS -> 3 blocks/CU). Iteration t reads buf t%3,
// stages tile t+2 into buf (t+2)%3; boundary wait vmcnt(4) keeps t+2's
// loads in flight across the barrier (T4).
// Q is pre-scaled by 0.125*log2(e); V tokens pre-permuted per 32-group:
// position p holds token ((p>>2)&1)*16 + (p>>3)*4 + (p&3); V-blocks
// transpose through LDS and write VT as full 16B/lane stores (R12).

#define TT_STRIDE 136  // ushorts per tile_T row (272 B): breaks bank alignment

__global__ __launch_bounds__(256) void gemm_qkv(const unsigned short* __restrict__ A,
                                                const unsigned short* __restrict__ BT,
                                                const float* __restrict__ bias,
                                                unsigned short* __restrict__ Qo,
                                                unsigned short* __restrict__ Ko,
                                                unsigned short* __restrict__ VTo) {
  // 48 KB: 3 A-bufs + 3 B-bufs of 128x32 bf16. The V-transpose tile
  // (17408 ushorts) aliases the whole region after the k-loop.
  __shared__ unsigned short smem[24576];
  int tid = threadIdx.x;
  int lane = tid & 63, w = tid >> 6, g = lane >> 4, c = lane & 15;
  int m0 = blockIdx.x * 128, n0 = blockIdx.y * 128;
  int wm = (w & 1) * 64, wn = (w >> 1) * 64;
  float4v acc[4][4] = {};

  // prologue: stage tiles 0 and 1 (8 DMAs/thread)
  stage128x32(A, smem + 0 * 4096, m0, 0, tid);
  stage128x32(BT, smem + 12288 + 0 * 4096, n0, 0, tid);
  stage128x32(A, smem + 1 * 4096, m0, 32, tid);
  stage128x32(BT, smem + 12288 + 1 * 4096, n0, 32, tid);
  asm volatile("s_waitcnt vmcnt(4)" ::: "memory");  // tile 0 landed; tile 1 in flight
  wg_barrier();

  int cb = 0;
  for (int t = 0; t < 32; ++t) {
    int nb = cb + 2; if (nb >= 3) nb -= 3;  // buffer of tile t+2
    const unsigned short* Ap = smem + cb * 4096;
    const unsigned short* Bp = smem + 12288 + cb * 4096;

    short8v af[4], bf[4];
#pragma unroll
    for (int i = 0; i < 4; i++) {
      int r = wm + i * 16 + c;
      af[i] = *(const short8v*)(Ap + r * 32 + (g ^ ((r >> 1) & 3)) * 8);
    }
#pragma unroll
    for (int j = 0; j < 4; j++) {
      int r = wn + j * 16 + c;
      bf[j] = *(const short8v*)(Bp + r * 32 + (g ^ ((r >> 1) & 3)) * 8);
    }

    if (t + 2 < 32) {
      stage128x32(A, smem + nb * 4096, m0, (t + 2) * 32, tid);
      stage128x32(BT, smem + 12288 + nb * 4096, n0, (t + 2) * 32, tid);
    }

    __builtin_amdgcn_s_setprio(1);
#pragma unroll
    for (int i = 0; i < 4; i++)
#pragma unroll
      for (int j = 0; j < 4; j++)
        acc[i][j] = MFMA_QK(af[i], bf[j], acc[i][j]);
    __builtin_amdgcn_s_setprio(0);

    if (t < 30) { asm volatile("s_waitcnt vmcnt(4)" ::: "memory"); }
    else        { asm volatile("s_waitcnt vmcnt(0)" ::: "memory"); }
    wg_barrier();
    cb = cb + 1 == 3 ? 0 : cb + 1;
  }

  int which = n0 >> 10;  // 0=Q 1=K 2=V, uniform per block
  if (which != 2) {
    // Q/K: direct writes ([b,h,n,d], 32B chunks; adjacent j-stores merge in L2)
#pragma unroll
    for (int j = 0; j < 4; j++) {
      int ng = n0 + wn + j * 16 + c;
      float bv = bias[ng];
      int h = (ng & 1023) >> 6, d = ng & 63;
#pragma unroll
      for (int i = 0; i < 4; i++) {
#pragma unroll
        for (int r = 0; r < 4; r++) {
          int mg = m0 + wm + i * 16 + g * 4 + r;
          int b = mg >> 11, n = mg & 2047;
          float v = acc[i][j][r] + bv;
          if (which == 0)
            Qo[((size_t)(b * 16 + h) * 2048 + n) * 64 + d] = f2bf(v * 0.18033688011112042f);
          else
            Ko[((size_t)(b * 16 + h) * 2048 + n) * 64 + d] = f2bf(v);
        }
      }
    }
  } else {
    // V: transpose through LDS -> full-line n-major VT writes.
    __syncthreads();  // k-loop fully done; safe to reuse smem as tile_T
#pragma unroll
    for (int j = 0; j < 4; j++) {
      int nl = wn + j * 16 + c;          // n_local = hl*64 + d
      float bv = bias[n0 + nl];
#pragma unroll
      for (int i = 0; i < 4; i++) {
        int ml = wm + i * 16 + g * 4;    // token_local (4 consecutive via r)
        unsigned p0 = pk_bf16(acc[i][j][0] + bv, acc[i][j][1] + bv);
        unsigned p1 = pk_bf16(acc[i][j][2] + bv, acc[i][j][3] + bv);
        *(unsigned*)(smem + nl * TT_STRIDE + ml) = p0;
        *(unsigned*)(smem + nl * TT_STRIDE + ml + 2) = p1;
      }
    }
    __syncthreads();
    // write phase: 16B/lane = permuted-octet gather (tokens P*4+0..3 and +16)
    int rr = lane >> 4, tc = lane & 15;
    int P = tc & 3, g32 = tc >> 2;
    int b = m0 >> 11, mloc = m0 & 2047;
    int h0 = (n0 & 1023) >> 6;
#pragma unroll
    for (int s = 0; s < 8; s++) {
      int row = w * 32 + s * 4 + rr;     // n_local
      int h = h0 + (row >> 6), d = row & 63;
      const unsigned short* bp = smem + row * TT_STRIDE + g32 * 32 + P * 4;
      union { unsigned long long q[2]; ushort8v v; } u;
      u.q[0] = *(const unsigned long long*)(bp);
      u.q[1] = *(const unsigned long long*)(bp + 16);
      size_t gaddr = ((size_t)(b * 16 + h) * 64 + d) * 2048 + mloc + g32 * 32 + P * 8;
      *(ushort8v*)(VTo + gaddr) = u.v;
    }
  }
}

// ---------------------------------------------------------------- attention
// R17: wave-private K/V LDS, ZERO barriers. R14's counters showed MFMA
// (2794 cyc/CU-iter) + non-MFMA VALU (3556) summing to the measured 6946 —
// the pipes run serially because all waves lockstep on __syncthreads every
// tile. Now each wave owns a 16 KB LDS slice (K 32x64 + VT 64x32, dbuf) and
// stages its own next 32-key chunk (8 cp16), synchronized only by its own
// counted vmcnt(8) — no block barrier, waves free-drift, one wave's exp
// VALU hides another's MFMA (m114 mechanism). V stays in LDS (R13/R16
// proved global-V is latency-bound). 64 q-rows/wave, grid 512, 2 blocks/CU.
// Swizzles bank-checked: K rows 8 groups x 2 lanes (free); V sigma =
// g ^ (d&2) ^ ((d>>2)&1) -> 2 lanes/bank-group (free). Fragment math and
// global VT octet mapping identical to R14.

#define NTOK 2048

__device__ __forceinline__ short8v exppack(float4v a, float4v b2) {
  a.x = EXP2F(a.x); a.y = EXP2F(a.y); a.z = EXP2F(a.z); a.w = EXP2F(a.w);
  b2.x = EXP2F(b2.x); b2.y = EXP2F(b2.y); b2.z = EXP2F(b2.z); b2.w = EXP2F(b2.w);
  union { unsigned u[4]; short8v s; } cv;
  cv.u[0] = pk_bf16(a.x, a.y);
  cv.u[1] = pk_bf16(a.z, a.w);
  cv.u[2] = pk_bf16(b2.x, b2.y);
  cv.u[3] = pk_bf16(b2.z, b2.w);
  return cv.s;
}

__global__ __launch_bounds__(256, 2) void attn_kernel(const unsigned short* __restrict__ Qg,
                                                      const unsigned short* __restrict__ Kg,
                                                      const unsigned short* __restrict__ VTg,
                                                      unsigned short* __restrict__ Og) {
  // 64 KB: wave w owns [w*8192, w*8192+8192) ushorts = 2 bufs x (K 2048 | V 2048)
  __shared__ unsigned short smem[32768];

  int tid = threadIdx.x;
  int lane = tid & 63, w = tid >> 6, g = lane >> 4, c = lane & 15;
  // XCD-locality swizzle: 512 blocks = 8 XCDs x (8 bh) x (8 q-chunks of 256)
  int id = blockIdx.x;
  int xcd = id & 7, within = id >> 3;
  int bh = xcd * 8 + (within >> 3);
  int q0 = (within & 7) * 256;

  const unsigned short* Qb = Qg + (size_t)bh * NTOK * 64;
  const unsigned short* Kb = Kg + (size_t)bh * NTOK * 64;
  const unsigned short* VTb = VTg + (size_t)bh * 64 * NTOK;

  unsigned short* wbase = smem + w * 8192;

  // Q fragments straight from global (one-time; 16B/lane); 64 rows per wave
  short8v qf[4][2];
#pragma unroll
  for (int nt = 0; nt < 4; nt++)
#pragma unroll
    for (int kk = 0; kk < 2; kk++)
      qf[nt][kk] = *(const short8v*)(Qb + (size_t)(q0 + w * 64 + nt * 16 + c) * 64 +
                                     kk * 32 + g * 8);

  short8v ones8;
#pragma unroll
  for (int i = 0; i < 8; i++) ones8[i] = (short)0x3F80;

  float4v lacc[4] = {};
  float4v o[4][4] = {};

  // ---- per-wave staging of one 32-key chunk into buffer pb (8 cp16/lane)
  // K tile: 32 rows x 64 cols; stored unit u = row*8+slot, slot holds logical
  //   chunk slot^(row&7). V tile: 64 d-rows x 32 keys; stored unit u = d*4+s,
  //   s holds logical octet s^m(d), m(d) = (d&2)^((d>>2)&1).
#define STAGE_CHUNK(pb_, ch32_)                                                   \
  {                                                                               \
    int kt_ = (ch32_) * 32;                                                       \
    unsigned short* kd_ = wbase + (pb_) * 4096;                                   \
    unsigned short* vd_ = kd_ + 2048;                                             \
    _Pragma("unroll")                                                             \
    for (int p_ = 0; p_ < 4; p_++) {                                              \
      int u_ = p_ * 64 + lane;                                                    \
      int row_ = u_ >> 3, sl_ = u_ & 7;                                           \
      int ch_ = sl_ ^ (row_ & 7);                                                 \
      async_cp16(Kb + (size_t)(kt_ + row_) * 64 + ch_ * 8, kd_ + u_ * 8);         \
    }                                                                             \
    _Pragma("unroll")                                                             \
    for (int p_ = 0; p_ < 4; p_++) {                                              \
      int u_ = p_ * 64 + lane;                                                    \
      int d_ = u_ >> 2, s_ = u_ & 3;                                              \
      int j_ = s_ ^ ((d_ & 2) ^ ((d_ >> 2) & 1));                                 \
      async_cp16(VTb + (size_t)d_ * 2048 + kt_ + j_ * 8, vd_ + u_ * 8);           \
    }                                                                             \
  }

  // prologue: stage chunk 0 into buf 0
  STAGE_CHUNK(0, 0)

  for (int ch32 = 0; ch32 < 64; ch32++) {
    int pb = ch32 & 1;
    if (ch32 + 1 < 64) {
      STAGE_CHUNK(1 - pb, ch32 + 1)
      asm volatile("s_waitcnt vmcnt(8)" ::: "memory");  // chunk ch32 landed
    } else {
      asm volatile("s_waitcnt vmcnt(0)" ::: "memory");
    }

    const unsigned short* Kp = wbase + pb * 4096;
    const unsigned short* Vp = Kp + 2048;

    // QK: 32 keys (2 row-halves) x 64 q-rows (4 nt) x K=64 (2 kk)
    float4v st[2][4] = {};
    __builtin_amdgcn_s_setprio(1);
#pragma unroll
    for (int mth = 0; mth < 2; mth++) {
      int row = mth * 16 + c;
      short8v kf[2];
#pragma unroll
      for (int kk = 0; kk < 2; kk++) {
        int sl = (kk * 4 + g) ^ (row & 7);
        kf[kk] = *(const short8v*)(Kp + row * 64 + sl * 8);
      }
#pragma unroll
      for (int nt = 0; nt < 4; nt++)
#pragma unroll
        for (int kk = 0; kk < 2; kk++)
          st[mth][nt] = MFMA_QK(kf[kk], qf[nt][kk], st[mth][nt]);
    }
    __builtin_amdgcn_s_setprio(0);

    short8v pa8[4];
#pragma unroll
    for (int nt = 0; nt < 4; nt++) pa8[nt] = exppack(st[0][nt], st[1][nt]);

    __builtin_amdgcn_s_setprio(1);
#pragma unroll
    for (int nt_o = 0; nt_o < 4; nt_o++) {
      int d = nt_o * 16 + c;
      int s = g ^ ((d & 2) ^ ((d >> 2) & 1));
      short8v vb8 = *(const short8v*)(Vp + d * 32 + s * 8);
#pragma unroll
      for (int mt = 0; mt < 4; mt++)
        o[mt][nt_o] = MFMA_QK(pa8[mt], vb8, o[mt][nt_o]);
    }
#pragma unroll
    for (int mt = 0; mt < 4; mt++)
      lacc[mt] = MFMA_QK(pa8[mt], ones8, lacc[mt]);
    __builtin_amdgcn_s_setprio(0);
  }

  // epilogue: lacc[mt][r] = L[q] in exactly o's row layout; no cross-lane
  int b = bh >> 4, h = bh & 15;
#pragma unroll
  for (int mt = 0; mt < 4; mt++) {
    float4v li;
#pragma unroll
    for (int r = 0; r < 4; r++) li[r] = 1.0f / lacc[mt][r];
#pragma unroll
    for (int nt_o = 0; nt_o < 4; nt_o++) {
      float4v v = o[mt][nt_o] * li;
      int col = h * 64 + nt_o * 16 + c;
      int rowbase = b * NTOK + q0 + w * 64 + mt * 16 + g * 4;
#pragma unroll
      for (int r = 0; r < 4; r++)
        Og[(size_t)(rowbase + r) * 1024 + col] = f2bf(v[r]);
    }
  }
}

// ---------------------------------------------------------------- proj GEMM
// R15: same counted-vmcnt 3-buffer pipeline at 128x128 / 256 threads.
__global__ __launch_bounds__(256) void gemm_proj(const unsigned short* __restrict__ A,
                                                 const unsigned short* __restrict__ BT,
                                                 const float* __restrict__ bias,
                                                 float* __restrict__ out) {
  __shared__ unsigned short smem[24576];  // 3 A-bufs + 3 B-bufs
  int tid = threadIdx.x;
  int lane = tid & 63, w = tid >> 6, g = lane >> 4, c = lane & 15;
  int m0 = blockIdx.x * 128, n0 = blockIdx.y * 128;
  int wm = (w & 1) * 64, wn = (w >> 1) * 64;
  float4v acc[4][4] = {};

  stage128x32(A, smem + 0 * 4096, m0, 0, tid);
  stage128x32(BT, smem + 12288 + 0 * 4096, n0, 0, tid);
  stage128x32(A, smem + 1 * 4096, m0, 32, tid);
  stage128x32(BT, smem + 12288 + 1 * 4096, n0, 32, tid);
  asm volatile("s_waitcnt vmcnt(4)" ::: "memory");
  wg_barrier();

  int cb = 0;
  for (int t = 0; t < 32; ++t) {
    int nb = cb + 2; if (nb >= 3) nb -= 3;
    const unsigned short* Ap = smem + cb * 4096;
    const unsigned short* Bp = smem + 12288 + cb * 4096;

    short8v af[4], bf[4];
#pragma unroll
    for (int i = 0; i < 4; i++) {
      int r = wm + i * 16 + c;
      af[i] = *(const short8v*)(Ap + r * 32 + (g ^ ((r >> 1) & 3)) * 8);
    }
#pragma unroll
    for (int j = 0; j < 4; j++) {
      int r = wn + j * 16 + c;
      bf[j] = *(const short8v*)(Bp + r * 32 + (g ^ ((r >> 1) & 3)) * 8);
    }

    if (t + 2 < 32) {
      stage128x32(A, smem + nb * 4096, m0, (t + 2) * 32, tid);
      stage128x32(BT, smem + 12288 + nb * 4096, n0, (t + 2) * 32, tid);
    }

    __builtin_amdgcn_s_setprio(1);
#pragma unroll
    for (int i = 0; i < 4; i++)
#pragma unroll
      for (int j = 0; j < 4; j++)
        acc[i][j] = MFMA_QK(af[i], bf[j], acc[i][j]);
    __builtin_amdgcn_s_setprio(0);

    if (t < 30) { asm volatile("s_waitcnt vmcnt(4)" ::: "memory"); }
    else        { asm volatile("s_waitcnt vmcnt(0)" ::: "memory"); }
    wg_barrier();
    cb = cb + 1 == 3 ? 0 : cb + 1;
  }

#pragma unroll
  for (int j = 0; j < 4; j++) {
    int ng = n0 + wn + j * 16 + c;
    float bv = bias[ng];
#pragma unroll
    for (int i = 0; i < 4; i++) {
#pragma unroll
      for (int r = 0; r < 4; r++) {
        int mg = m0 + wm + i * 16 + g * 4 + r;
        out[(size_t)mg * 1024 + ng] = acc[i][j][r] + bv;
      }
    }
  }
}

// ---------------------------------------------------------------- launch

extern "C" void kernel_launch(void* const* d_in, const int* in_sizes, int n_in,
                              void* d_out, int out_size, void* d_ws, size_t ws_size,
                              hipStream_t stream) {
  (void)in_sizes; (void)n_in; (void)out_size; (void)ws_size;
  const float* x = (const float*)d_in[0];
  const float* w_qkv = (const float*)d_in[1];
  const float* b_qkv = (const float*)d_in[2];
  const float* w_proj = (const float*)d_in[3];
  const float* b_proj = (const float*)d_in[4];
  float* out = (float*)d_out;

  unsigned short* x_bf = (unsigned short*)d_ws;          // 8192*1024
  unsigned short* wqkvT = x_bf + (size_t)8192 * 1024;    // 3072*1024
  unsigned short* wprojT = wqkvT + (size_t)3072 * 1024;  // 1024*1024
  unsigned short* qws = wprojT + (size_t)1024 * 1024;    // 64*2048*64
  unsigned short* kws = qws + (size_t)8388608;
  unsigned short* vtws = kws + (size_t)8388608;
  unsigned short* aws = vtws + (size_t)8388608;          // attn out 8192*1024

  cvt_f32_bf16<<<8192, 256, 0, stream>>>(x, x_bf);
  transpose_w<<<dim3(16, 48), 256, 0, stream>>>(w_qkv, wqkvT, 1024, 3072);
  transpose_w<<<dim3(16, 16), 256, 0, stream>>>(w_proj, wprojT, 1024, 1024);
  gemm_qkv<<<dim3(64, 24), 256, 0, stream>>>(x_bf, wqkvT, b_qkv, qws, kws, vtws);
  attn_kernel<<<512, 256, 0, stream>>>(qws, kws, vtws, aws);
  gemm_proj<<<dim3(64, 8), 256, 0, stream>>>(aws, wprojT, b_proj, out);
}

// Round 10
// 263.900 us; speedup vs baseline: 1.1812x; 1.0170x over previous
//
#include <hip/hip_runtime.h>

typedef __attribute__((ext_vector_type(8))) short short8v;
typedef __attribute__((ext_vector_type(4))) short short4v;
typedef __attribute__((ext_vector_type(4))) float float4v;
typedef __attribute__((ext_vector_type(4))) unsigned short ushort4v;
typedef __attribute__((ext_vector_type(8))) unsigned short ushort8v;

#define GLOBAL_AS __attribute__((address_space(1)))
#define LDS_AS __attribute__((address_space(3)))

__device__ __forceinline__ void async_cp16(const void* g, void* l) {
  __builtin_amdgcn_global_load_lds((const GLOBAL_AS void*)g, (LDS_AS void*)l, 16, 0, 0);
}

__device__ __forceinline__ unsigned short f2bf(float f) {
  unsigned u = __float_as_uint(f);
  u += 0x7fffu + ((u >> 16) & 1u);   // RNE to bf16
  return (unsigned short)(u >> 16);
}

// amdgcn target-builtins are invisible in the host pass — gate all probes.
#if defined(__HIP_DEVICE_COMPILE__)
#if __has_builtin(__builtin_amdgcn_exp2f)
#define EXP2F(x) __builtin_amdgcn_exp2f(x)
#else
#define EXP2F(x) exp2f(x)
#endif
#else
#define EXP2F(x) exp2f(x)
#endif

#if defined(__HIP_DEVICE_COMPILE__) && __has_builtin(__builtin_amdgcn_cvt_pk_bf16_f32)
typedef __attribute__((ext_vector_type(2))) __bf16 bf16x2v;
__device__ __forceinline__ unsigned pk_bf16(float a, float b) {
  bf16x2v r = __builtin_amdgcn_cvt_pk_bf16_f32(a, b);
  return __builtin_bit_cast(unsigned, r);
}
#else
__device__ __forceinline__ unsigned pk_bf16(float a, float b) {
  return (unsigned)f2bf(a) | ((unsigned)f2bf(b) << 16);
}
#endif

#define MFMA_QK(a, b, c) __builtin_amdgcn_mfma_f32_16x16x32_bf16(a, b, c, 0, 0, 0)

// Raw workgroup barrier with compiler memory fence (no implicit vmcnt(0) drain).
__device__ __forceinline__ void wg_barrier() {
  asm volatile("" ::: "memory");
  __builtin_amdgcn_s_barrier();
  asm volatile("" ::: "memory");
}

// ---------------------------------------------------------------- converters

__global__ __launch_bounds__(256) void cvt_f32_bf16(const float* __restrict__ src,
                                                    unsigned short* __restrict__ dst) {
  int i = blockIdx.x * 256 + threadIdx.x;
  float4 v = ((const float4*)src)[i];
  ushort4v o;
  o.x = f2bf(v.x); o.y = f2bf(v.y); o.z = f2bf(v.z); o.w = f2bf(v.w);
  ((ushort4v*)dst)[i] = o;
}

// src: K x N fp32  ->  dst: N x K bf16 (transposed)
__global__ __launch_bounds__(256) void transpose_w(const float* __restrict__ src,
                                                   unsigned short* __restrict__ dst,
                                                   int K, int N) {
  __shared__ float tile[64][65];
  int k0 = blockIdx.x * 64, n0 = blockIdx.y * 64;
  int t = threadIdx.x;
  int tc = t & 15, tr = t >> 4;
#pragma unroll
  for (int p = 0; p < 4; p++) {
    int r = tr + p * 16;
    float4 v = *(const float4*)(src + (size_t)(k0 + r) * N + n0 + tc * 4);
    tile[r][tc * 4 + 0] = v.x; tile[r][tc * 4 + 1] = v.y;
    tile[r][tc * 4 + 2] = v.z; tile[r][tc * 4 + 3] = v.w;
  }
  __syncthreads();
#pragma unroll
  for (int p = 0; p < 4; p++) {
    int rn = tr + p * 16;
    ushort4v o;
    o.x = f2bf(tile[tc * 4 + 0][rn]);
    o.y = f2bf(tile[tc * 4 + 1][rn]);
    o.z = f2bf(tile[tc * 4 + 2][rn]);
    o.w = f2bf(tile[tc * 4 + 3][rn]);
    *(ushort4v*)(dst + (size_t)(n0 + rn) * K + k0 + tc * 4) = o;
  }
}

// ---------------------------------------------------------------- GEMM staging
// Swizzle (HW-verified 0 bank conflicts in R2): physical 16B slot s of row
// holds logical chunk s ^ ((row>>1)&3). global_load_lds dest stays linear;
// the GLOBAL source is pre-swizzled; ds_read applies the same XOR.
// 128 rows x 32 cols bf16, 256 threads, 2 cp16/thread.
__device__ __forceinline__ void stage128x32(const unsigned short* __restrict__ src,
                                            unsigned short* dst, int r0, int k0, int tid) {
#pragma unroll
  for (int p = 0; p < 2; p++) {
    int idx = p * 256 + tid;
    int row = idx >> 2, s = idx & 3;
    int ch = s ^ ((row >> 1) & 3);
    async_cp16(src + (size_t)(r0 + row) * 1024 + k0 + ch * 8, dst + idx * 8);
  }
}

// ---------------------------------------------------------------- QKV GEMM
// R15: counted-vmcnt 3-buffer pipeline at the R1 geometry (128x128, 256
// threads, BK=32, 48 KB LDS -> 3 blocks/CU).
// R18: within-XCD 2D work swizzle. Old (64,24) grid put an XCD's concurrent
// working set at ~24 MB of A-tiles (>> 4MB L2) -> ~20 MB of A re-fetch
// (FETCH 41 vs 22 ideal). Now XCD x owns m-tiles [8x,8x+8) x all 24 n-tiles,
// mi-fast: every block on the XCD draws from the same 8 A-tiles (2 MB,
// L2-resident for the whole kernel). A fetched once (16 MB); B L3-absorbed.
// Q is pre-scaled by 0.125*log2(e); V tokens pre-permuted per 32-group:
// position p holds token ((p>>2)&1)*16 + (p>>3)*4 + (p&3); V-blocks
// transpose through LDS and write VT as full 16B/lane stores (R12).

#define TT_STRIDE 136  // ushorts per tile_T row (272 B): breaks bank alignment

__global__ __launch_bounds__(256) void gemm_qkv(const unsigned short* __restrict__ A,
                                                const unsigned short* __restrict__ BT,
                                                const float* __restrict__ bias,
                                                unsigned short* __restrict__ Qo,
                                                unsigned short* __restrict__ Ko,
                                                unsigned short* __restrict__ VTo) {
  // 48 KB: 3 A-bufs + 3 B-bufs of 128x32 bf16. The V-transpose tile
  // (17408 ushorts) aliases the whole region after the k-loop.
  __shared__ unsigned short smem[24576];
  int tid = threadIdx.x;
  int lane = tid & 63, w = tid >> 6, g = lane >> 4, c = lane & 15;
  // R18 swizzle: 1536 blocks = 8 XCDs x (8 mi x 24 ni), mi-fast
  int id = blockIdx.x;
  int xcd = id & 7, within = id >> 3;
  int m0 = (xcd * 8 + (within & 7)) * 128;
  int n0 = (within >> 3) * 128;
  int wm = (w & 1) * 64, wn = (w >> 1) * 64;
  float4v acc[4][4] = {};

  // prologue: stage tiles 0 and 1 (8 DMAs/thread)
  stage128x32(A, smem + 0 * 4096, m0, 0, tid);
  stage128x32(BT, smem + 12288 + 0 * 4096, n0, 0, tid);
  stage128x32(A, smem + 1 * 4096, m0, 32, tid);
  stage128x32(BT, smem + 12288 + 1 * 4096, n0, 32, tid);
  asm volatile("s_waitcnt vmcnt(4)" ::: "memory");  // tile 0 landed; tile 1 in flight
  wg_barrier();

  int cb = 0;
  for (int t = 0; t < 32; ++t) {
    int nb = cb + 2; if (nb >= 3) nb -= 3;  // buffer of tile t+2
    const unsigned short* Ap = smem + cb * 4096;
    const unsigned short* Bp = smem + 12288 + cb * 4096;

    short8v af[4], bf[4];
#pragma unroll
    for (int i = 0; i < 4; i++) {
      int r = wm + i * 16 + c;
      af[i] = *(const short8v*)(Ap + r * 32 + (g ^ ((r >> 1) & 3)) * 8);
    }
#pragma unroll
    for (int j = 0; j < 4; j++) {
      int r = wn + j * 16 + c;
      bf[j] = *(const short8v*)(Bp + r * 32 + (g ^ ((r >> 1) & 3)) * 8);
    }

    if (t + 2 < 32) {
      stage128x32(A, smem + nb * 4096, m0, (t + 2) * 32, tid);
      stage128x32(BT, smem + 12288 + nb * 4096, n0, (t + 2) * 32, tid);
    }

    __builtin_amdgcn_s_setprio(1);
#pragma unroll
    for (int i = 0; i < 4; i++)
#pragma unroll
      for (int j = 0; j < 4; j++)
        acc[i][j] = MFMA_QK(af[i], bf[j], acc[i][j]);
    __builtin_amdgcn_s_setprio(0);

    if (t < 30) { asm volatile("s_waitcnt vmcnt(4)" ::: "memory"); }
    else        { asm volatile("s_waitcnt vmcnt(0)" ::: "memory"); }
    wg_barrier();
    cb = cb + 1 == 3 ? 0 : cb + 1;
  }

  int which = n0 >> 10;  // 0=Q 1=K 2=V, uniform per block
  if (which != 2) {
    // Q/K: direct writes ([b,h,n,d], 32B chunks; adjacent j-stores merge in L2)
#pragma unroll
    for (int j = 0; j < 4; j++) {
      int ng = n0 + wn + j * 16 + c;
      float bv = bias[ng];
      int h = (ng & 1023) >> 6, d = ng & 63;
#pragma unroll
      for (int i = 0; i < 4; i++) {
#pragma unroll
        for (int r = 0; r < 4; r++) {
          int mg = m0 + wm + i * 16 + g * 4 + r;
          int b = mg >> 11, n = mg & 2047;
          float v = acc[i][j][r] + bv;
          if (which == 0)
            Qo[((size_t)(b * 16 + h) * 2048 + n) * 64 + d] = f2bf(v * 0.18033688011112042f);
          else
            Ko[((size_t)(b * 16 + h) * 2048 + n) * 64 + d] = f2bf(v);
        }
      }
    }
  } else {
    // V: transpose through LDS -> full-line n-major VT writes.
    __syncthreads();  // k-loop fully done; safe to reuse smem as tile_T
#pragma unroll
    for (int j = 0; j < 4; j++) {
      int nl = wn + j * 16 + c;          // n_local = hl*64 + d
      float bv = bias[n0 + nl];
#pragma unroll
      for (int i = 0; i < 4; i++) {
        int ml = wm + i * 16 + g * 4;    // token_local (4 consecutive via r)
        unsigned p0 = pk_bf16(acc[i][j][0] + bv, acc[i][j][1] + bv);
        unsigned p1 = pk_bf16(acc[i][j][2] + bv, acc[i][j][3] + bv);
        *(unsigned*)(smem + nl * TT_STRIDE + ml) = p0;
        *(unsigned*)(smem + nl * TT_STRIDE + ml + 2) = p1;
      }
    }
    __syncthreads();
    // write phase: 16B/lane = permuted-octet gather (tokens P*4+0..3 and +16)
    int rr = lane >> 4, tc = lane & 15;
    int P = tc & 3, g32 = tc >> 2;
    int b = m0 >> 11, mloc = m0 & 2047;
    int h0 = (n0 & 1023) >> 6;
#pragma unroll
    for (int s = 0; s < 8; s++) {
      int row = w * 32 + s * 4 + rr;     // n_local
      int h = h0 + (row >> 6), d = row & 63;
      const unsigned short* bp = smem + row * TT_STRIDE + g32 * 32 + P * 4;
      union { unsigned long long q[2]; ushort8v v; } u;
      u.q[0] = *(const unsigned long long*)(bp);
      u.q[1] = *(const unsigned long long*)(bp + 16);
      size_t gaddr = ((size_t)(b * 16 + h) * 64 + d) * 2048 + mloc + g32 * 32 + P * 8;
      *(ushort8v*)(VTo + gaddr) = u.v;
    }
  }
}

// ---------------------------------------------------------------- attention
// R14 (FROZEN): R4/R9 LDS structure + two-group issue pipeline. 92.6 us,
// conflicts 0. Five structural variants (R13 no-LDS, R16 4-wave, R17
// wave-private barrier-free) all regressed or were neutral; pipe-sum
// MfmaUtil+VALUBusy ~= 87% invariant -> issue/dependency floor for this
// algorithm shape at 2 blocks/CU. Do not touch without a new mechanism.

#define NTOK 2048
#define BK 64

__device__ __forceinline__ short8v exppack(float4v a, float4v b2) {
  a.x = EXP2F(a.x); a.y = EXP2F(a.y); a.z = EXP2F(a.z); a.w = EXP2F(a.w);
  b2.x = EXP2F(b2.x); b2.y = EXP2F(b2.y); b2.z = EXP2F(b2.z); b2.w = EXP2F(b2.w);
  union { unsigned u[4]; short8v s; } cv;
  cv.u[0] = pk_bf16(a.x, a.y);
  cv.u[1] = pk_bf16(a.z, a.w);
  cv.u[2] = pk_bf16(b2.x, b2.y);
  cv.u[3] = pk_bf16(b2.z, b2.w);
  return cv.s;
}

__global__ __launch_bounds__(256, 2) void attn_kernel(const unsigned short* __restrict__ Qg,
                                                      const unsigned short* __restrict__ Kg,
                                                      const unsigned short* __restrict__ VTg,
                                                      unsigned short* __restrict__ Og) {
  __shared__ unsigned short Ks[2][BK * 64];   // [buf][row][8 chunks, row-XOR swizzled]
  __shared__ unsigned short VTs[2][64 * BK];  // [buf][d][8 chunks, d-XOR swizzled]

  int tid = threadIdx.x;
  int lane = tid & 63, w = tid >> 6, g = lane >> 4, c = lane & 15;
  // XCD-locality swizzle: 512 blocks = 8 XCDs x (8 bh) x (8 q-chunks of 256)
  int id = blockIdx.x;
  int xcd = id & 7, within = id >> 3;
  int bh = xcd * 8 + (within >> 3);
  int q0 = (within & 7) * 256;

  const unsigned short* Qb = Qg + (size_t)bh * NTOK * 64;
  const unsigned short* Kb = Kg + (size_t)bh * NTOK * 64;
  const unsigned short* VTb = VTg + (size_t)bh * 64 * NTOK;

  // Q fragments straight from global (one-time; 16B/lane); 64 rows per wave
  short8v qf[4][2];
#pragma unroll
  for (int nt = 0; nt < 4; nt++)
#pragma unroll
    for (int kk = 0; kk < 2; kk++)
      qf[nt][kk] = *(const short8v*)(Qb + (size_t)(q0 + w * 64 + nt * 16 + c) * 64 +
                                     kk * 32 + g * 8);

  short8v ones8;
#pragma unroll
  for (int i = 0; i < 8; i++) ones8[i] = (short)0x3F80;

  float4v lacc[4] = {};
  float4v o[4][4] = {};

  // prologue: stage tile 0 into buf 0
#pragma unroll
  for (int p = 0; p < 2; p++) {
    int idx = p * 256 + tid;
    int row = idx >> 3, ch = idx & 7;
    async_cp16(Kb + (size_t)row * 64 + ((ch ^ (row & 7)) * 8), &Ks[0][idx * 8]);
    async_cp16(VTb + (size_t)row * NTOK + ((ch ^ (row & 7)) * 8), &VTs[0][idx * 8]);
  }

  for (int it = 0; it < NTOK / BK; it++) {
    int pb = it & 1;
    __syncthreads();  // drains own DMAs for tile it (issued a full phase ago)

    if (it + 1 < NTOK / BK) {
      int kt = (it + 1) * BK;
#pragma unroll
      for (int p = 0; p < 2; p++) {
        int idx = p * 256 + tid;
        int row = idx >> 3, ch = idx & 7;
        async_cp16(Kb + (size_t)(kt + row) * 64 + ((ch ^ (row & 7)) * 8),
                   &Ks[1 - pb][idx * 8]);
        async_cp16(VTb + (size_t)row * NTOK + kt + ((ch ^ (row & 7)) * 8),
                   &VTs[1 - pb][idx * 8]);
      }
    }

    const unsigned short* Kp = &Ks[pb][0];
    const unsigned short* Vp = &VTs[pb][0];

    float4v stA[2][4] = {};
    float4v stB[2][4] = {};

    // QK(t0) and QK(t1) both issued before any st is consumed: exp(t0)'s
    // VALU overlaps QK(t1)'s MFMA drain.
    __builtin_amdgcn_s_setprio(1);
#pragma unroll
    for (int mth = 0; mth < 2; mth++) {
      int row = mth * 16 + c;
      short8v kf[2];
#pragma unroll
      for (int kk = 0; kk < 2; kk++) {
        int ch = (kk * 4 + g) ^ (row & 7);
        kf[kk] = *(const short8v*)(Kp + row * 64 + ch * 8);
      }
#pragma unroll
      for (int nt = 0; nt < 4; nt++)
#pragma unroll
        for (int kk = 0; kk < 2; kk++)
          stA[mth][nt] = MFMA_QK(kf[kk], qf[nt][kk], stA[mth][nt]);
    }
#pragma unroll
    for (int mth = 0; mth < 2; mth++) {
      int row = (2 + mth) * 16 + c;
      short8v kf[2];
#pragma unroll
      for (int kk = 0; kk < 2; kk++) {
        int ch = (kk * 4 + g) ^ (row & 7);
        kf[kk] = *(const short8v*)(Kp + row * 64 + ch * 8);
      }
#pragma unroll
      for (int nt = 0; nt < 4; nt++)
#pragma unroll
        for (int kk = 0; kk < 2; kk++)
          stB[mth][nt] = MFMA_QK(kf[kk], qf[nt][kk], stB[mth][nt]);
    }
    __builtin_amdgcn_s_setprio(0);

    short8v pa8A[4];
#pragma unroll
    for (int nt = 0; nt < 4; nt++) pa8A[nt] = exppack(stA[0][nt], stA[1][nt]);

    __builtin_amdgcn_s_setprio(1);
#pragma unroll
    for (int nt_o = 0; nt_o < 4; nt_o++) {
      int d = nt_o * 16 + c;
      int s = g ^ (d & 7);                 // t=0: unit g holds the lane's 8 keys
      short8v vb8 = *(const short8v*)(Vp + d * BK + s * 8);
#pragma unroll
      for (int mt = 0; mt < 4; mt++)
        o[mt][nt_o] = MFMA_QK(pa8A[mt], vb8, o[mt][nt_o]);
    }
#pragma unroll
    for (int mt = 0; mt < 4; mt++)
      lacc[mt] = MFMA_QK(pa8A[mt], ones8, lacc[mt]);
    __builtin_amdgcn_s_setprio(0);

    // exp/pack(t1) overlaps PV(t0)'s MFMA drain
    short8v pa8B[4];
#pragma unroll
    for (int nt = 0; nt < 4; nt++) pa8B[nt] = exppack(stB[0][nt], stB[1][nt]);

    __builtin_amdgcn_s_setprio(1);
#pragma unroll
    for (int nt_o = 0; nt_o < 4; nt_o++) {
      int d = nt_o * 16 + c;
      int s = (4 + g) ^ (d & 7);           // t=1: unit 4+g
      short8v vb8 = *(const short8v*)(Vp + d * BK + s * 8);
#pragma unroll
      for (int mt = 0; mt < 4; mt++)
        o[mt][nt_o] = MFMA_QK(pa8B[mt], vb8, o[mt][nt_o]);
    }
#pragma unroll
    for (int mt = 0; mt < 4; mt++)
      lacc[mt] = MFMA_QK(pa8B[mt], ones8, lacc[mt]);
    __builtin_amdgcn_s_setprio(0);
  }

  // epilogue: lacc[mt][r] = L[q] in exactly o's row layout; no cross-lane
  int b = bh >> 4, h = bh & 15;
#pragma unroll
  for (int mt = 0; mt < 4; mt++) {
    float4v li;
#pragma unroll
    for (int r = 0; r < 4; r++) li[r] = 1.0f / lacc[mt][r];
#pragma unroll
    for (int nt_o = 0; nt_o < 4; nt_o++) {
      float4v v = o[mt][nt_o] * li;
      int col = h * 64 + nt_o * 16 + c;
      int rowbase = b * NTOK + q0 + w * 64 + mt * 16 + g * 4;
#pragma unroll
      for (int r = 0; r < 4; r++)
        Og[(size_t)(rowbase + r) * 1024 + col] = f2bf(v[r]);
    }
  }
}

// ---------------------------------------------------------------- proj GEMM
// R15 pipeline + R18 within-XCD 2D work swizzle (XCD owns 8 m x 8 n tiles;
// per-XCD A working set 2 MB, L2-resident).
__global__ __launch_bounds__(256) void gemm_proj(const unsigned short* __restrict__ A,
                                                 const unsigned short* __restrict__ BT,
                                                 const float* __restrict__ bias,
                                                 float* __restrict__ out) {
  __shared__ unsigned short smem[24576];  // 3 A-bufs + 3 B-bufs
  int tid = threadIdx.x;
  int lane = tid & 63, w = tid >> 6, g = lane >> 4, c = lane & 15;
  // 512 blocks = 8 XCDs x (8 mi x 8 ni), mi-fast
  int id = blockIdx.x;
  int xcd = id & 7, within = id >> 3;
  int m0 = (xcd * 8 + (within & 7)) * 128;
  int n0 = (within >> 3) * 128;
  int wm = (w & 1) * 64, wn = (w >> 1) * 64;
  float4v acc[4][4] = {};

  stage128x32(A, smem + 0 * 4096, m0, 0, tid);
  stage128x32(BT, smem + 12288 + 0 * 4096, n0, 0, tid);
  stage128x32(A, smem + 1 * 4096, m0, 32, tid);
  stage128x32(BT, smem + 12288 + 1 * 4096, n0, 32, tid);
  asm volatile("s_waitcnt vmcnt(4)" ::: "memory");
  wg_barrier();

  int cb = 0;
  for (int t = 0; t < 32; ++t) {
    int nb = cb + 2; if (nb >= 3) nb -= 3;
    const unsigned short* Ap = smem + cb * 4096;
    const unsigned short* Bp = smem + 12288 + cb * 4096;

    short8v af[4], bf[4];
#pragma unroll
    for (int i = 0; i < 4; i++) {
      int r = wm + i * 16 + c;
      af[i] = *(const short8v*)(Ap + r * 32 + (g ^ ((r >> 1) & 3)) * 8);
    }
#pragma unroll
    for (int j = 0; j < 4; j++) {
      int r = wn + j * 16 + c;
      bf[j] = *(const short8v*)(Bp + r * 32 + (g ^ ((r >> 1) & 3)) * 8);
    }

    if (t + 2 < 32) {
      stage128x32(A, smem + nb * 4096, m0, (t + 2) * 32, tid);
      stage128x32(BT, smem + 12288 + nb * 4096, n0, (t + 2) * 32, tid);
    }

    __builtin_amdgcn_s_setprio(1);
#pragma unroll
    for (int i = 0; i < 4; i++)
#pragma unroll
      for (int j = 0; j < 4; j++)
        acc[i][j] = MFMA_QK(af[i], bf[j], acc[i][j]);
    __builtin_amdgcn_s_setprio(0);

    if (t < 30) { asm volatile("s_waitcnt vmcnt(4)" ::: "memory"); }
    else        { asm volatile("s_waitcnt vmcnt(0)" ::: "memory"); }
    wg_barrier();
    cb = cb + 1 == 3 ? 0 : cb + 1;
  }

#pragma unroll
  for (int j = 0; j < 4; j++) {
    int ng = n0 + wn + j * 16 + c;
    float bv = bias[ng];
#pragma unroll
    for (int i = 0; i < 4; i++) {
#pragma unroll
      for (int r = 0; r < 4; r++) {
        int mg = m0 + wm + i * 16 + g * 4 + r;
        out[(size_t)mg * 1024 + ng] = acc[i][j][r] + bv;
      }
    }
  }
}

// ---------------------------------------------------------------- launch

extern "C" void kernel_launch(void* const* d_in, const int* in_sizes, int n_in,
                              void* d_out, int out_size, void* d_ws, size_t ws_size,
                              hipStream_t stream) {
  (void)in_sizes; (void)n_in; (void)out_size; (void)ws_size;
  const float* x = (const float*)d_in[0];
  const float* w_qkv = (const float*)d_in[1];
  const float* b_qkv = (const float*)d_in[2];
  const float* w_proj = (const float*)d_in[3];
  const float* b_proj = (const float*)d_in[4];
  float* out = (float*)d_out;

  unsigned short* x_bf = (unsigned short*)d_ws;          // 8192*1024
  unsigned short* wqkvT = x_bf + (size_t)8192 * 1024;    // 3072*1024
  unsigned short* wprojT = wqkvT + (size_t)3072 * 1024;  // 1024*1024
  unsigned short* qws = wprojT + (size_t)1024 * 1024;    // 64*2048*64
  unsigned short* kws = qws + (size_t)8388608;
  unsigned short* vtws = kws + (size_t)8388608;
  unsigned short* aws = vtws + (size_t)8388608;          // attn out 8192*1024

  cvt_f32_bf16<<<8192, 256, 0, stream>>>(x, x_bf);
  transpose_w<<<dim3(16, 48), 256, 0, stream>>>(w_qkv, wqkvT, 1024, 3072);
  transpose_w<<<dim3(16, 16), 256, 0, stream>>>(w_proj, wprojT, 1024, 1024);
  gemm_qkv<<<1536, 256, 0, stream>>>(x_bf, wqkvT, b_qkv, qws, kws, vtws);
  attn_kernel<<<512, 256, 0, stream>>>(qws, kws, vtws, aws);
  gemm_proj<<<512, 256, 0, stream>>>(aws, wprojT, b_proj, out);
}